// Round 12
// baseline (178.240 us; speedup 1.0000x reference)
//
#include <hip/hip_runtime.h>
#include <stdint.h>

// Problem constants
constexpr int NBATCH = 4;
constexpr int CH     = 256;   // channels
constexpr int LEN    = 4096;  // sequence length
constexpr int LPOOL  = 1024;  // pooled length (LEN/4)
constexpr int NH     = 4;     // heads
constexpr int HD     = 64;    // head dim

typedef __attribute__((ext_vector_type(8))) short short8;   // 8 bf16 in 4 VGPRs
typedef __attribute__((ext_vector_type(4))) float float4e;  // MFMA C/D

__device__ __forceinline__ unsigned short f2bf(float f) {
    union { unsigned int i; float f; } v; v.f = f;
    unsigned int lsb = (v.i >> 16) & 1u;
    v.i += 0x7fffu + lsb;
    return (unsigned short)(v.i >> 16);
}
// pack two floats -> two bf16 (round-half-up via +0x8000, then byte-perm)
__device__ __forceinline__ unsigned pack2bf(float lo, float hi) {
    unsigned a = __float_as_uint(lo) + 0x8000u;
    unsigned b = __float_as_uint(hi) + 0x8000u;
    return __builtin_amdgcn_perm(b, a, 0x07060302u);
}

// ---------------------------------------------------------------------------
// Setup kernel. Blocks:
//   0..1023   : transpose+pool over x  -> xbf [N,L,C], poolT [N,L2,C]
//   1024..1151: cast Wq -> Wbf slot0, Wo -> Wbf slot3
//   1152..1159: COMPOSE Wk' = (Wk.diag(scale)).Wa, Wv' = (Wv.diag(scale)).Wa
//               (BN folded into the weights; the xa stage disappears) into
//               Wbf slot1 (512 rows x 256, K-contig) + bkv[512] biases
//               bk' = Wk@shift + bk, bv' = Wv@shift + bv.
__global__ __launch_bounds__(256) void transpool_setup(
    const float* __restrict__ x, unsigned short* __restrict__ xbf,
    unsigned short* __restrict__ poolT,
    const float* __restrict__ w0, const float* __restrict__ w1,
    const float* __restrict__ w2, const float* __restrict__ w3,
    const float* __restrict__ w4, unsigned short* __restrict__ outW,
    const float* __restrict__ g1, const float* __restrict__ b1,
    const float* __restrict__ m1, const float* __restrict__ v1,
    const float* __restrict__ g2, const float* __restrict__ b2,
    const float* __restrict__ m2, const float* __restrict__ v2,
    const float* __restrict__ bk, const float* __restrict__ bv,
    float* __restrict__ bkv)
{
    __shared__ union {
        struct { float T[64][65]; float P16[64][17]; } tp;
        struct { float scF[256]; float shF[256]; float bp[128][8];
                 unsigned short Cs[2 * 128 * 72]; } cp;
    } sh;
    int b = blockIdx.x, t = threadIdx.x;

    if (b >= 1024) {
        int sb = b - 1024;
        if (sb < 128) {
            // weight cast: Wq -> slot0, Wo -> slot3
            int w = sb >> 6;
            int off = (sb & 63) * 1024 + t * 4;
            const float* src = (w == 0) ? w0 : w3;
            int slot = (w == 0) ? 0 : 3;
            float4 v = *(const float4*)(src + off);
            uint2 pk;
            pk.x = pack2bf(v.x, v.y);
            pk.y = pack2bf(v.z, v.w);
            *(uint2*)(outW + slot * 65536 + off) = pk;
            return;
        }
        // ---- compose blocks (8) ----
        int cb = sb - 128;
        int mat = cb >> 2;                 // 0: K (w1), 1: V (w2)
        int tile = cb & 3;
        int rowT = (tile >> 1) * 128, colT = (tile & 1) * 128;
        const float* Wsrc = mat ? w2 : w1;
        const float* bsrc = mat ? bv : bk;

        {   // BN affine into LDS
            float inv1 = g1[t] * rsqrtf(v1[t] + 1e-5f);
            float inv2 = g2[t] * rsqrtf(v2[t] + 1e-5f);
            sh.cp.scF[t] = inv1 * inv2;
            sh.cp.shF[t] = (b1[t] - m1[t] * inv1) * inv2 + (b2[t] - m2[t] * inv2);
        }
        __syncthreads();

        unsigned short* As = sh.cp.Cs;
        unsigned short* Bs = sh.cp.Cs + 128 * 72;
        int wave = t >> 6, lane = t & 63, m = lane & 15, quad = lane >> 4;
        int wm = wave & 1, wn = wave >> 1;
        float4e acc[4][4] = {};
        float regB[4] = {};

        for (int cc = 0; cc < 256; cc += 64) {
            __syncthreads();
            // A' = Wsrc row-block, scaled by scF[c], cast bf16
            #pragma unroll
            for (int i = 0; i < 4; i++) {
                int idx = t + i * 256, row = idx >> 3, c8 = idx & 7;
                const float* sp = Wsrc + (size_t)(rowT + row) * 256 + cc + c8 * 8;
                float4 a = *(const float4*)sp, b4 = *(const float4*)(sp + 4);
                int ci = cc + c8 * 8;
                regB[i] += a.x * sh.cp.shF[ci]     + a.y * sh.cp.shF[ci + 1]
                         + a.z * sh.cp.shF[ci + 2] + a.w * sh.cp.shF[ci + 3]
                         + b4.x * sh.cp.shF[ci + 4] + b4.y * sh.cp.shF[ci + 5]
                         + b4.z * sh.cp.shF[ci + 6] + b4.w * sh.cp.shF[ci + 7];
                uint4 pk;
                pk.x = pack2bf(a.x * sh.cp.scF[ci],     a.y * sh.cp.scF[ci + 1]);
                pk.y = pack2bf(a.z * sh.cp.scF[ci + 2], a.w * sh.cp.scF[ci + 3]);
                pk.z = pack2bf(b4.x * sh.cp.scF[ci + 4], b4.y * sh.cp.scF[ci + 5]);
                pk.w = pack2bf(b4.z * sh.cp.scF[ci + 6], b4.w * sh.cp.scF[ci + 7]);
                *(uint4*)&As[row * 72 + c8 * 8] = pk;
            }
            // B'[j][c] = Wa[c][colT+j]  (transpose during stage)
            #pragma unroll
            for (int i = 0; i < 8; i++) {
                int idx = t + i * 256, c = idx >> 5, j4 = (idx & 31) * 4;
                float4 w = *(const float4*)(w4 + (size_t)(cc + c) * 256 + colT + j4);
                Bs[(j4 + 0) * 72 + c] = f2bf(w.x);
                Bs[(j4 + 1) * 72 + c] = f2bf(w.y);
                Bs[(j4 + 2) * 72 + c] = f2bf(w.z);
                Bs[(j4 + 3) * 72 + c] = f2bf(w.w);
            }
            __syncthreads();
            #pragma unroll
            for (int kc = 0; kc < 2; kc++) {
                short8 af[4], bfr[4];
                #pragma unroll
                for (int i = 0; i < 4; i++)
                    af[i] = *(const short8*)&As[(wm * 64 + i * 16 + m) * 72 + kc * 32 + quad * 8];
                #pragma unroll
                for (int j = 0; j < 4; j++)
                    bfr[j] = *(const short8*)&Bs[(wn * 64 + j * 16 + m) * 72 + kc * 32 + quad * 8];
                #pragma unroll
                for (int i = 0; i < 4; i++)
                    #pragma unroll
                    for (int j = 0; j < 4; j++)
                        acc[i][j] = __builtin_amdgcn_mfma_f32_16x16x32_bf16(af[i], bfr[j], acc[i][j], 0, 0, 0);
            }
        }
        __syncthreads();
        if (colT == 0) {
            #pragma unroll
            for (int i = 0; i < 4; i++) {
                int idx = t + i * 256;
                sh.cp.bp[idx >> 3][idx & 7] = regB[i];
            }
        }
        // restage tile to row-major bf16 and store to Wbf slot1
        unsigned short* TO = sh.cp.Cs;   // [128][136]
        #pragma unroll
        for (int i = 0; i < 4; i++) {
            int rowL = wm * 64 + i * 16 + quad * 4;
            #pragma unroll
            for (int j = 0; j < 4; j++) {
                int colL = wn * 64 + j * 16 + m;
                float4e c = acc[i][j];
                TO[(rowL + 0) * 136 + colL] = f2bf(c[0]);
                TO[(rowL + 1) * 136 + colL] = f2bf(c[1]);
                TO[(rowL + 2) * 136 + colL] = f2bf(c[2]);
                TO[(rowL + 3) * 136 + colL] = f2bf(c[3]);
            }
        }
        __syncthreads();
        #pragma unroll
        for (int w = 0; w < 8; w++) {
            int idx = t + w * 256, row = idx >> 4, ch = idx & 15;
            *(uint4*)(outW + 65536 + (size_t)(mat * 256 + rowT + row) * 256 + colT + ch * 8) =
                *(const uint4*)&TO[row * 136 + ch * 8];
        }
        if (colT == 0 && t < 128) {
            float s = bsrc[rowT + t];
            #pragma unroll
            for (int u = 0; u < 8; u++) s += sh.cp.bp[t][u];
            bkv[mat * 256 + rowT + t] = s;
        }
        return;
    }

    // ---- transpose + pool blocks ----
    int n = b >> 8, c0 = ((b >> 6) & 3) * 64, l0 = (b & 63) * 64;
    const float* xp = x + ((size_t)n * CH + c0) * LEN + l0;
    #pragma unroll
    for (int i = 0; i < 4; i++) {
        int idx = t + i * 256;
        int c = idx >> 4, l4 = idx & 15;
        float4 v = *(const float4*)(xp + (size_t)c * LEN + l4 * 4);
        sh.tp.T[c][l4 * 4 + 0] = v.x; sh.tp.T[c][l4 * 4 + 1] = v.y;
        sh.tp.T[c][l4 * 4 + 2] = v.z; sh.tp.T[c][l4 * 4 + 3] = v.w;
        sh.tp.P16[c][l4] = (v.x + v.y + v.z + v.w) * 0.25f
                         + fmaxf(fmaxf(v.x, v.y), fmaxf(v.z, v.w));
    }
    __syncthreads();
    unsigned short* op = xbf + ((size_t)n * LEN + l0) * CH + c0;
    #pragma unroll
    for (int i = 0; i < 4; i++) {
        int idx = t + i * 256;
        int l = idx >> 4, c4 = idx & 15;
        uint2 pk;
        pk.x = pack2bf(sh.tp.T[c4 * 4 + 0][l], sh.tp.T[c4 * 4 + 1][l]);
        pk.y = pack2bf(sh.tp.T[c4 * 4 + 2][l], sh.tp.T[c4 * 4 + 3][l]);
        *(uint2*)(op + (size_t)l * CH + c4 * 4) = pk;
    }
    int p0 = l0 >> 2;
    #pragma unroll
    for (int k = 0; k < 2; k++) {
        int p = (t >> 5) + k * 8;
        int c2 = (t & 31) * 2;
        unsigned pk = pack2bf(sh.tp.P16[c2][p], sh.tp.P16[c2 + 1][p]);
        *(unsigned*)(poolT + ((size_t)n * LPOOL + p0 + p) * CH + c0 + c2) = pk;
    }
}

// ---------------------------------------------------------------------------
// Shared MFMA GEMM body: D[i][j] = sum_k A[i][k]*B[j][k], K=256 bf16.
// outF (f32 [row][col], ld NN) OR bf16 out1 (col*cs1+row, rows<rowSplit) /
// out2 ((row-rowSplit)*rs2+col). All dst pointers pre-offset by batch.
__device__ __forceinline__ void gemm_body(
    const unsigned short* __restrict__ Ab,   // A + rowTile*256
    const unsigned short* __restrict__ Bb,   // B + n*bBatch + col0*256
    int rowTile, int col0,
    const float* __restrict__ biasRow,
    float* __restrict__ outF, int NN,
    unsigned short* __restrict__ out1, int cs1,
    unsigned short* __restrict__ out2, int rs2, int rowSplit,
    float outScale, unsigned short* smem)
{
    unsigned short* As = smem;
    unsigned short* Bs = smem + 128 * 72;
    int t = threadIdx.x;
    int wave = t >> 6, lane = t & 63, m = lane & 15, quad = lane >> 4;
    int wm = wave & 1, wn = wave >> 1;

    float4e acc[4][4] = {};

    for (int kk = 0; kk < 256; kk += 64) {
        #pragma unroll
        for (int i = 0; i < 4; i++) {
            int idx = t + i * 256;
            int row = idx >> 3, ch = idx & 7;
            *(uint4*)&As[row * 72 + ch * 8] = *(const uint4*)(Ab + (size_t)row * 256 + kk + ch * 8);
            *(uint4*)&Bs[row * 72 + ch * 8] = *(const uint4*)(Bb + (size_t)row * 256 + kk + ch * 8);
        }
        __syncthreads();
        #pragma unroll
        for (int kc = 0; kc < 2; kc++) {
            short8 af[4], bfr[4];
            #pragma unroll
            for (int i = 0; i < 4; i++)
                af[i] = *(const short8*)&As[(wm * 64 + i * 16 + m) * 72 + kc * 32 + quad * 8];
            #pragma unroll
            for (int j = 0; j < 4; j++)
                bfr[j] = *(const short8*)&Bs[(wn * 64 + j * 16 + m) * 72 + kc * 32 + quad * 8];
            #pragma unroll
            for (int i = 0; i < 4; i++)
                #pragma unroll
                for (int j = 0; j < 4; j++)
                    acc[i][j] = __builtin_amdgcn_mfma_f32_16x16x32_bf16(af[i], bfr[j], acc[i][j], 0, 0, 0);
        }
        __syncthreads();
    }

    if (outF) {
        float* TOf = (float*)smem;   // [64][128]
        #pragma unroll
        for (int half = 0; half < 2; half++) {
            __syncthreads();
            if (wm == half) {
                #pragma unroll
                for (int i = 0; i < 4; i++) {
                    int rowL = i * 16 + quad * 4;
                    int rowG = rowTile + half * 64 + rowL;
                    float br[4];
                    #pragma unroll
                    for (int r = 0; r < 4; r++)
                        br[r] = biasRow ? biasRow[rowG + r] : 0.0f;
                    #pragma unroll
                    for (int j = 0; j < 4; j++) {
                        int colL = wn * 64 + j * 16 + m;
                        float4e c = acc[i][j];
                        #pragma unroll
                        for (int r = 0; r < 4; r++)
                            TOf[(rowL + r) * 128 + colL] = (c[r] + br[r]) * outScale;
                    }
                }
            }
            __syncthreads();
            #pragma unroll
            for (int w = 0; w < 8; w++) {
                int idx = t + w * 256;
                int row = idx >> 5, c4 = idx & 31;
                *(float4*)(outF + (size_t)(rowTile + half * 64 + row) * NN + col0 + c4 * 4) =
                    *(const float4*)&TOf[row * 128 + c4 * 4];
            }
        }
        return;
    }

    bool mode2 = (rowTile >= rowSplit);
    unsigned short* TO = smem;
    #pragma unroll
    for (int i = 0; i < 4; i++) {
        int rowL = wm * 64 + i * 16 + quad * 4;
        int rowG = rowTile + rowL;
        float br[4];
        #pragma unroll
        for (int r = 0; r < 4; r++)
            br[r] = biasRow ? biasRow[rowG + r] : 0.0f;
        #pragma unroll
        for (int j = 0; j < 4; j++) {
            int colL = wn * 64 + j * 16 + m;
            float4e c = acc[i][j];
            float v0 = (c[0] + br[0]) * outScale;
            float v1 = (c[1] + br[1]) * outScale;
            float v2 = (c[2] + br[2]) * outScale;
            float v3 = (c[3] + br[3]) * outScale;
            if (!mode2) {
                uint2 pk;
                pk.x = pack2bf(v0, v1);
                pk.y = pack2bf(v2, v3);
                *(uint2*)&TO[colL * 136 + rowL] = pk;
            } else {
                TO[(rowL + 0) * 136 + colL] = f2bf(v0);
                TO[(rowL + 1) * 136 + colL] = f2bf(v1);
                TO[(rowL + 2) * 136 + colL] = f2bf(v2);
                TO[(rowL + 3) * 136 + colL] = f2bf(v3);
            }
        }
    }
    __syncthreads();
    if (!mode2) {
        #pragma unroll
        for (int w = 0; w < 8; w++) {
            int idx = t + w * 256;
            int l = idx >> 4, ch = idx & 15;
            *(uint4*)(out1 + (size_t)(col0 + l) * cs1 + rowTile + ch * 8) =
                *(const uint4*)&TO[l * 136 + ch * 8];
        }
    } else {
        int rowBase = rowTile - rowSplit;
        #pragma unroll
        for (int w = 0; w < 8; w++) {
            int idx = t + w * 256;
            int row = idx >> 4, ch = idx & 15;
            *(uint4*)(out2 + (size_t)(rowBase + row) * rs2 + col0 + ch * 8) =
                *(const uint4*)&TO[row * 136 + ch * 8];
        }
    }
}

// ---------------------------------------------------------------------------
// Merged q + k + v projections (both depend only on setup).
// bx 0..63: q tiles (32 col x 2 row). bx 64..95: kv tiles (8 col x 4 row,
// A = composed [Wk';Wv'] 512 rows at Wbf slot1).
__global__ __launch_bounds__(256) void gemm_qkv(
    const unsigned short* __restrict__ Wbf,
    const unsigned short* __restrict__ xbf,
    const unsigned short* __restrict__ poolT,
    const float* __restrict__ bq, const float* __restrict__ bkv,
    unsigned short* __restrict__ Qbf,
    unsigned short* __restrict__ Kbf,
    unsigned short* __restrict__ Vbf)
{
    __shared__ unsigned short smem[2 * 128 * 72];
    int n = blockIdx.z, bx = blockIdx.x;
    if (bx < 64) {
        int colT = (bx & 31) * 128, rowT = (bx >> 5) * 128;
        gemm_body(Wbf + (size_t)rowT * 256,
                  xbf + (size_t)n * LEN * CH + (size_t)colT * 256,
                  rowT, colT, bq,
                  nullptr, 0,
                  Qbf + (size_t)n * LEN * CH, 256,
                  nullptr, 0, 1 << 30,
                  0.18033688f, smem);   // log2(e)/8
    } else {
        int j = bx - 64;
        int colT = (j & 7) * 128, rowT = (j >> 3) * 128;
        gemm_body(Wbf + 65536 + (size_t)rowT * 256,
                  poolT + (size_t)n * LPOOL * CH + (size_t)colT * 256,
                  rowT, colT, bkv,
                  nullptr, 0,
                  Kbf + (size_t)n * LPOOL * CH, 256,
                  Vbf + (size_t)n * LPOOL * CH, LPOOL, 256,
                  1.0f, smem);
    }
}

// ---------------------------------------------------------------------------
// o-projection: out = Wo @ O + bo -> f32 d_out [N,C,L]
__global__ __launch_bounds__(256) void gemm_o(
    const unsigned short* __restrict__ Wbf3,
    const unsigned short* __restrict__ Obf,
    const float* __restrict__ bo, float* __restrict__ out)
{
    __shared__ unsigned short smem[2 * 128 * 72];
    int n = blockIdx.z;
    int colT = blockIdx.x * 128, rowT = blockIdx.y * 128;
    gemm_body(Wbf3 + (size_t)rowT * 256,
              Obf + (size_t)n * LEN * CH + (size_t)colT * 256,
              rowT, colT, bo,
              out + (size_t)n * CH * LEN, LEN,
              nullptr, 0, nullptr, 0, 1 << 30,
              1.0f, smem);
}

// ---------------------------------------------------------------------------
// MFMA flash attention: fixed-shift softmax, register-resident P,
// 32 q/wave (128-q blocks, grid 512), double-buffered K/V LDS with register
// prefetch. __launch_bounds__(256,2) grants the VGPR budget (no spill).
__global__ __launch_bounds__(256, 2) void attn_mfma(
    const unsigned short* __restrict__ Qb,
    const unsigned short* __restrict__ Kb,
    const unsigned short* __restrict__ Vb,
    unsigned short* __restrict__ Obf)
{
    __shared__ unsigned short Ks[2][128 * 72];   // K-tile [key][e], pad 8
    __shared__ unsigned short Vs[2][64 * 136];   // V^T-tile [e][key], pad 8

    int qb = blockIdx.x;
    int h  = blockIdx.y;
    int n  = blockIdx.z;
    int t  = threadIdx.x;
    int wave = t >> 6, lane = t & 63;
    int m = lane & 15, quad = lane >> 4;
    int l0 = qb * 128 + wave * 32;

    const unsigned short* qp = Qb + ((size_t)n * LEN + l0 + m) * CH + h * HD + quad * 8;
    short8 bQ[2][2];
    bQ[0][0] = *(const short8*)qp;
    bQ[0][1] = *(const short8*)(qp + 32);
    bQ[1][0] = *(const short8*)(qp + 16 * CH);
    bQ[1][1] = *(const short8*)(qp + 16 * CH + 32);

    float4e Oa[2][4] = {};
    float l_run[2] = {0.0f, 0.0f};

    const unsigned short* KgBase = Kb + (size_t)n * LPOOL * CH + h * HD;
    const unsigned short* VgBase = Vb + ((size_t)n * CH + h * HD) * LPOOL;
    const float NEG = -17.312340f;   // -12 * log2(e)

    int krow[4], kch[4], ve[4], vch[4];
    #pragma unroll
    for (int i = 0; i < 4; i++) {
        int idx = t + i * 256;
        krow[i] = idx >> 3; kch[i] = idx & 7;
        ve[i]   = idx >> 4; vch[i] = idx & 15;
    }

    uint4 kreg[4], vreg[4];
    #pragma unroll
    for (int i = 0; i < 4; i++) {
        kreg[i] = *(const uint4*)(KgBase + (size_t)krow[i] * CH + kch[i] * 8);
        vreg[i] = *(const uint4*)(VgBase + (size_t)ve[i] * LPOOL + vch[i] * 8);
    }
    #pragma unroll
    for (int i = 0; i < 4; i++) {
        *(uint4*)&Ks[0][krow[i] * 72 + kch[i] * 8] = kreg[i];
        *(uint4*)&Vs[0][ve[i] * 136 + vch[i] * 8] = vreg[i];
    }
    __syncthreads();

    for (int kt = 0; kt < 8; kt++) {
        int cur = kt & 1;
        if (kt < 7) {
            const unsigned short* Kg2 = KgBase + (size_t)(kt + 1) * 128 * CH;
            const unsigned short* Vg2 = VgBase + (kt + 1) * 128;
            #pragma unroll
            for (int i = 0; i < 4; i++) {
                kreg[i] = *(const uint4*)(Kg2 + (size_t)krow[i] * CH + kch[i] * 8);
                vreg[i] = *(const uint4*)(Vg2 + (size_t)ve[i] * LPOOL + vch[i] * 8);
            }
        }

        #pragma unroll
        for (int ch2 = 0; ch2 < 4; ch2++) {
            const unsigned short* kpE = &Ks[cur][(ch2 * 32 + m) * 72 + quad * 8];
            const unsigned short* kpO = kpE + 16 * 72;
            short8 aE0 = *(const short8*)kpE;
            short8 aE1 = *(const short8*)(kpE + 32);
            short8 aO0 = *(const short8*)kpO;
            short8 aO1 = *(const short8*)(kpO + 32);
            union { unsigned u[4]; short8 s; } aV[4];
            #pragma unroll
            for (int eb = 0; eb < 4; eb++) {
                const unsigned short* vp = &Vs[cur][(eb * 16 + m) * 136 + ch2 * 32 + quad * 4];
                *(uint2*)&aV[eb].u[0] = *(const uint2*)vp;
                *(uint2*)&aV[eb].u[2] = *(const uint2*)(vp + 16);
            }

            #pragma unroll
            for (int qf = 0; qf < 2; qf++) {
                float4e cE = {NEG, NEG, NEG, NEG};
                cE = __builtin_amdgcn_mfma_f32_16x16x32_bf16(aE0, bQ[qf][0], cE, 0, 0, 0);
                cE = __builtin_amdgcn_mfma_f32_16x16x32_bf16(aE1, bQ[qf][1], cE, 0, 0, 0);
                float4e cO = {NEG, NEG, NEG, NEG};
                cO = __builtin_amdgcn_mfma_f32_16x16x32_bf16(aO0, bQ[qf][0], cO, 0, 0, 0);
                cO = __builtin_amdgcn_mfma_f32_16x16x32_bf16(aO1, bQ[qf][1], cO, 0, 0, 0);
                float pE0 = exp2f(cE[0]), pE1 = exp2f(cE[1]);
                float pE2 = exp2f(cE[2]), pE3 = exp2f(cE[3]);
                float pO0 = exp2f(cO[0]), pO1 = exp2f(cO[1]);
                float pO2 = exp2f(cO[2]), pO3 = exp2f(cO[3]);
                l_run[qf] += ((pE0 + pE1) + (pE2 + pE3)) + ((pO0 + pO1) + (pO2 + pO3));
                union { unsigned u[4]; short8 s; } bP;
                bP.u[0] = pack2bf(pE0, pE1);
                bP.u[1] = pack2bf(pE2, pE3);
                bP.u[2] = pack2bf(pO0, pO1);
                bP.u[3] = pack2bf(pO2, pO3);
                #pragma unroll
                for (int eb = 0; eb < 4; eb++)
                    Oa[qf][eb] = __builtin_amdgcn_mfma_f32_16x16x32_bf16(aV[eb].s, bP.s, Oa[qf][eb], 0, 0, 0);
            }
        }

        if (kt < 7) {
            int nxt = cur ^ 1;
            #pragma unroll
            for (int i = 0; i < 4; i++) {
                *(uint4*)&Ks[nxt][krow[i] * 72 + kch[i] * 8] = kreg[i];
                *(uint4*)&Vs[nxt][ve[i] * 136 + vch[i] * 8] = vreg[i];
            }
            __syncthreads();
        }
    }

    #pragma unroll
    for (int qf = 0; qf < 2; qf++) {
        float l = l_run[qf];
        l += __shfl_xor(l, 16);
        l += __shfl_xor(l, 32);
        float inv = 1.0f / l;
        unsigned short* op = Obf + ((size_t)n * LEN + l0 + qf * 16 + m) * CH + h * HD;
        #pragma unroll
        for (int eb = 0; eb < 4; eb++) {
            uint2 pk;
            pk.x = pack2bf(Oa[qf][eb][0] * inv, Oa[qf][eb][1] * inv);
            pk.y = pack2bf(Oa[qf][eb][2] * inv, Oa[qf][eb][3] * inv);
            *(uint2*)(op + eb * 16 + quad * 4) = pk;
        }
    }
}

// ---------------------------------------------------------------------------
extern "C" void kernel_launch(void* const* d_in, const int* in_sizes, int n_in,
                              void* d_out, int out_size, void* d_ws, size_t ws_size,
                              hipStream_t stream)
{
    const float* x  = (const float*)d_in[0];
    const float* Wq = (const float*)d_in[1];
    const float* bq = (const float*)d_in[2];
    const float* Wk = (const float*)d_in[3];
    const float* bk = (const float*)d_in[4];
    const float* Wv = (const float*)d_in[5];
    const float* bv = (const float*)d_in[6];
    const float* Wo = (const float*)d_in[7];
    const float* bo = (const float*)d_in[8];
    const float* Wa = (const float*)d_in[9];
    const float* g1 = (const float*)d_in[10];
    const float* b1 = (const float*)d_in[11];
    const float* m1 = (const float*)d_in[12];
    const float* v1 = (const float*)d_in[13];
    const float* g2 = (const float*)d_in[14];
    const float* b2 = (const float*)d_in[15];
    const float* m2 = (const float*)d_in[16];
    const float* v2 = (const float*)d_in[17];

    float* wsf = (float*)d_ws;
    float* bkv = wsf;                 // 512
    unsigned short* Wbf   = (unsigned short*)(wsf + 512);           // 5*65536
    unsigned short* xbf   = Wbf + 5 * 65536;                        // [N,L,C]
    unsigned short* poolT = xbf   + (size_t)NBATCH * LEN * CH;      // [N,L2,C]
    unsigned short* Kbf   = poolT + (size_t)NBATCH * LPOOL * CH;    // [N,L2,C]
    unsigned short* Vbf   = Kbf   + (size_t)NBATCH * LPOOL * CH;    // [N,C,L2]
    unsigned short* Qbf   = Vbf   + (size_t)NBATCH * LPOOL * CH;    // [N,L,C]
    unsigned short* Obf   = Qbf   + (size_t)NBATCH * LEN * CH;      // [N,L,C]

    // 1. transpose+pool, Wq/Wo cast, composed Wk'/Wv' + bkv
    transpool_setup<<<1160, 256, 0, stream>>>(x, xbf, poolT,
        Wq, Wk, Wv, Wo, Wa, Wbf,
        g1, b1, m1, v1, g2, b2, m2, v2, bk, bv, bkv);

    // 2. q + k + v projections in one launch
    gemm_qkv<<<dim3(96, 1, 4), 256, 0, stream>>>(
        Wbf, xbf, poolT, bq, bkv, Qbf, Kbf, Vbf);

    // 3. attention -> Obf [N,L,C] bf16
    attn_mfma<<<dim3(LEN / 128, NH, NBATCH), 256, 0, stream>>>(Qbf, Kbf, Vbf, Obf);

    // 4. out = Wo @ O + bo -> f32 d_out [N,C,L]
    gemm_o<<<dim3(32, 2, 4), 256, 0, stream>>>(
        Wbf + 3 * 65536, Obf, bo, (float*)d_out);
}